// Round 8
// baseline (32.626 us; speedup 1.0000x reference)
//
#include <hip/hip_runtime.h>
#include <hip/hip_fp16.h>

#define RS 7
#define SR 2
#define PD 10
#define CH (PD * RS * RS)   // 490
#define SCALE (1.0f / 16.0f)
#define HH 100
#define WW 100
#define NPLANE (HH * WW)    // 10000
#define NP4 (NPLANE / 4)    // 2500
#define NB 4                // batch size
#define MAXN 4096           // LDS list capacity
#define TPB 512

__device__ __forceinline__ unsigned pack_h2(float a, float b) {
    __half2 h = __floats2half2_rn(a, b);     // lo=a (plane A), hi=b (plane B)
    return __builtin_bit_cast(unsigned, h);
}
__device__ __forceinline__ __half2 u2h2(unsigned u) {
    return __builtin_bit_cast(__half2, u);
}

// ---- coords once, sample BOTH planes via packed fp16 math ----
__device__ __forceinline__ void psroi_sample2_h2(
    const unsigned* __restrict__ plane,      // half2-packed pair plane
    float sw, float sh, float bw, float bh, int ph, int pw,
    float& outA, float& outB)
{
    float accA = 0.0f, accB = 0.0f;
    #pragma unroll
    for (int iy = 0; iy < SR; ++iy) {
        float y  = sh + ((float)ph + ((float)iy + 0.5f) * (1.0f / SR)) * bh;
        bool  vy = (y >= -1.0f) && (y <= (float)HH);
        float yy = fmaxf(y, 0.0f);
        int   y0 = min((int)floorf(yy), HH - 1);
        int   y1 = min(y0 + 1, HH - 1);
        float yc = (y0 >= HH - 1) ? (float)y0 : yy;
        float ly = yc - (float)y0;
        float hy = 1.0f - ly;
        #pragma unroll
        for (int ix = 0; ix < SR; ++ix) {
            float x  = sw + ((float)pw + ((float)ix + 0.5f) * (1.0f / SR)) * bw;
            bool  vx = (x >= -1.0f) && (x <= (float)WW);
            float xx = fmaxf(x, 0.0f);
            int   x0 = min((int)floorf(xx), WW - 1);
            int   x1 = min(x0 + 1, WW - 1);
            float xc = (x0 >= WW - 1) ? (float)x0 : xx;
            float lx = xc - (float)x0;
            float hx = 1.0f - lx;
            if (vy && vx) {
                __half2 v00 = u2h2(plane[y0 * WW + x0]);
                __half2 v01 = u2h2(plane[y0 * WW + x1]);
                __half2 v10 = u2h2(plane[y1 * WW + x0]);
                __half2 v11 = u2h2(plane[y1 * WW + x1]);
                __half2 s = __hmul2(__float2half2_rn(hy * hx), v00);
                s = __hfma2(__float2half2_rn(hy * lx), v01, s);
                s = __hfma2(__float2half2_rn(ly * hx), v10, s);
                s = __hfma2(__float2half2_rn(ly * lx), v11, s);
                accA += __low2float(s);
                accB += __high2float(s);
            }
        }
    }
    outA = accA * (1.0f / (SR * SR));
    outB = accB * (1.0f / (SR * SR));
}

// ---- fused pair kernel: one block per (batch, ph, pw, c-pair) ----
__global__ __launch_bounds__(TPB) void psroi_pair_kernel(
    const float* __restrict__ feat, const float* __restrict__ rois,
    float* __restrict__ out, int N)
{
    __shared__ __align__(16) unsigned plane[NPLANE];   // 40 KB half2-packed pair
    __shared__ unsigned short list[MAXN];              // 8 KB
    __shared__ int lcnt;

    int tid = threadIdx.x;
    if (tid == 0) lcnt = 0;
    __syncthreads();

    // bijective XCD-aware chunking (nwg=980, not %8==0)
    int bid = blockIdx.x, nwg = gridDim.x;
    int q = nwg >> 3, rr = nwg & 7;
    int xcd = bid & 7, idx = bid >> 3;
    int g = (xcd < rr ? xcd * (q + 1) : rr * (q + 1) + (xcd - rr) * q) + idx;

    int b   = g / (CH / 2);              // /245
    int r5  = g - b * (CH / 2);
    int j   = r5 / (RS * RS);            // c-pair index 0..4
    int pp  = r5 - j * (RS * RS);        // (ph,pw) 0..48
    int ph  = pp / RS, pw = pp - ph * RS;
    int cin1 = (2 * j) * (RS * RS) + pp;
    int cin2 = cin1 + (RS * RS);

    // 1) issue BOTH fp32 planes as float4 loads into registers (10 in flight)
    const float4* srcA = (const float4*)(feat + (size_t)(b * CH + cin1) * NPLANE);
    const float4* srcB = (const float4*)(feat + (size_t)(b * CH + cin2) * NPLANE);
    int i0 = tid, i1 = tid + TPB, i2 = tid + 2 * TPB, i3 = tid + 3 * TPB, i4 = tid + 4 * TPB;
    float4 a0 = srcA[i0], a1 = srcA[i1], a2 = srcA[i2], a3 = srcA[i3];
    float4 b0 = srcB[i0], b1 = srcB[i1], b2 = srcB[i2], b3 = srcB[i3];
    float4 a4, b4;
    if (i4 < NP4) { a4 = srcA[i4]; b4 = srcB[i4]; }

    // 2) scan ROI batch ids while plane loads are in flight; ballot-compact
    int lane = tid & 63;
    for (int k0 = 0; k0 < N; k0 += TPB) {
        int  k = k0 + tid;
        bool m = false;
        if (k < N) m = ((int)rois[(size_t)k * 5] == b);
        unsigned long long msk = __ballot(m);
        if (m) {
            int rank   = __popcll(msk & ((1ull << lane) - 1ull));
            int leader = __ffsll((long long)msk) - 1;
            int base   = 0;
            if (lane == leader) base = atomicAdd(&lcnt, (int)__popcll(msk));
            base = __shfl(base, leader);
            list[base + rank] = (unsigned short)k;
        }
    }

    // 3) convert to packed half2 (lo=A, hi=B) and commit to LDS
    uint4* d4 = (uint4*)plane;
    #define CVT4(dst_i, a, b) do {                                        \
        uint4 u_;                                                          \
        u_.x = pack_h2((a).x, (b).x); u_.y = pack_h2((a).y, (b).y);       \
        u_.z = pack_h2((a).z, (b).z); u_.w = pack_h2((a).w, (b).w);       \
        d4[dst_i] = u_; } while (0)
    CVT4(i0, a0, b0); CVT4(i1, a1, b1); CVT4(i2, a2, b2); CVT4(i3, a3, b3);
    if (i4 < NP4) CVT4(i4, a4, b4);
    #undef CVT4
    __syncthreads();

    // 4) compute: coords once per ROI, packed taps give two outputs
    int cnt = lcnt;
    for (int i = tid; i < cnt; i += TPB) {
        int n = list[i];
        const float* rp = rois + (size_t)n * 5;
        float sw = rp[1] * SCALE - 0.5f;
        float sh = rp[2] * SCALE - 0.5f;
        float bw = (rp[3] * SCALE - 0.5f - sw) * (1.0f / RS);
        float bh = (rp[4] * SCALE - 0.5f - sh) * (1.0f / RS);
        float vA, vB;
        psroi_sample2_h2(plane, sw, sh, bw, bh, ph, pw, vA, vB);
        out[(size_t)n * CH + cin1] = vA;
        out[(size_t)n * CH + cin2] = vB;
    }
}

// ---- fp32 direct-gather fallback for N > MAXN ----
__device__ __forceinline__ float psroi_sample_f32(const float* __restrict__ plane,
                                                  float sw, float sh, float bw, float bh,
                                                  int ph, int pw)
{
    float acc = 0.0f;
    #pragma unroll
    for (int iy = 0; iy < SR; ++iy) {
        float y  = sh + ((float)ph + ((float)iy + 0.5f) * (1.0f / SR)) * bh;
        bool  vy = (y >= -1.0f) && (y <= (float)HH);
        float yy = fmaxf(y, 0.0f);
        int   y0 = min((int)floorf(yy), HH - 1);
        int   y1 = min(y0 + 1, HH - 1);
        float yc = (y0 >= HH - 1) ? (float)y0 : yy;
        float ly = yc - (float)y0;
        float hy = 1.0f - ly;
        #pragma unroll
        for (int ix = 0; ix < SR; ++ix) {
            float x  = sw + ((float)pw + ((float)ix + 0.5f) * (1.0f / SR)) * bw;
            bool  vx = (x >= -1.0f) && (x <= (float)WW);
            float xx = fmaxf(x, 0.0f);
            int   x0 = min((int)floorf(xx), WW - 1);
            int   x1 = min(x0 + 1, WW - 1);
            float xc = (x0 >= WW - 1) ? (float)x0 : xx;
            float lx = xc - (float)x0;
            float hx = 1.0f - lx;
            float v00 = plane[y0 * WW + x0];
            float v01 = plane[y0 * WW + x1];
            float v10 = plane[y1 * WW + x0];
            float v11 = plane[y1 * WW + x1];
            float v = hy * (hx * v00 + lx * v01) + ly * (hx * v10 + lx * v11);
            if (vy && vx) acc += v;
        }
    }
    return acc * (1.0f / (SR * SR));
}

__global__ __launch_bounds__(256) void psroi_naive_kernel(
    const float* __restrict__ feat, const float* __restrict__ rois,
    float* __restrict__ out, int total)
{
    int o = blockIdx.x * blockDim.x + threadIdx.x;
    if (o >= total) return;
    int cin = o % CH;
    int n   = o / CH;
    int pw  = cin % RS;
    int ph  = (cin / RS) % RS;
    const float* r = rois + (size_t)n * 5;
    int bidx = (int)r[0];
    float sw = r[1] * SCALE - 0.5f;
    float sh = r[2] * SCALE - 0.5f;
    float bw = (r[3] * SCALE - 0.5f - sw) * (1.0f / RS);
    float bh = (r[4] * SCALE - 0.5f - sh) * (1.0f / RS);
    const float* base = feat + (size_t)(bidx * CH + cin) * NPLANE;
    out[o] = psroi_sample_f32(base, sw, sh, bw, bh, ph, pw);
}

extern "C" void kernel_launch(void* const* d_in, const int* in_sizes, int n_in,
                              void* d_out, int out_size, void* d_ws, size_t ws_size,
                              hipStream_t stream) {
    const float* feat = (const float*)d_in[0];
    const float* rois = (const float*)d_in[1];
    float* out = (float*)d_out;
    int N = in_sizes[1] / 5;

    if (N <= MAXN) {
        psroi_pair_kernel<<<NB * CH / 2, TPB, 0, stream>>>(feat, rois, out, N);
    } else {
        int total = N * CH;
        psroi_naive_kernel<<<(total + 255) / 256, 256, 0, stream>>>(feat, rois, out, total);
    }
}